// Round 9
// baseline (128.316 us; speedup 1.0000x reference)
//
#include <hip/hip_runtime.h>
#include <hip/hip_bf16.h>

#define CI 32
#define CC 64
#define NBATCH 2
#define NPIX 9216          // 96*96
#define NSD 24             // m-splits for k_denom (NPIX/24 = 384)
#define LOG2E 1.4426950408889634f

typedef __attribute__((ext_vector_type(8))) short s16x8;
typedef __attribute__((ext_vector_type(4))) short s16x4;
typedef __attribute__((ext_vector_type(4))) float f32x4;
typedef __attribute__((ext_vector_type(2))) unsigned int u32x2;
typedef __attribute__((ext_vector_type(4))) unsigned int u32x4;

static __device__ __forceinline__ unsigned cvtpk(float a, float b) {
    unsigned d;
    asm("v_cvt_pk_bf16_f32 %0, %1, %2" : "=v"(d) : "v"(a), "v"(b));
    return d;
}
static __device__ __forceinline__ short f2b(float f) {
    union { float f; unsigned u; } v; v.f = f;
    return (short)((v.u + 0x7FFFu + ((v.u >> 16) & 1u)) >> 16);
}
static __device__ __forceinline__ float b2f(short s) {
    union { unsigned u; float f; } v; v.u = ((unsigned)(unsigned short)s) << 16;
    return v.f;
}
static __device__ __forceinline__ s16x8 asS16x8(u32x4 v) {
    union { u32x4 u; s16x8 s; } c; c.u = v; return c.s;
}

// ---------------------------------------------------------------------------
// K0: 1x1 conv projections. grid (NBATCH*NPIX/64, 3). 256 thr: 4-way c-split
//  mode 0: kC[b][c][ncol(n)] (bf16, K-permuted columns)
//  mode 1: vT[b][n][c]   mode 2: qT[b][n][c] * log2(e)
// kC column permutation: within each 32-block, storage col for physical
// offset p is: p<16 -> (p>>2)*8 + (p&3) ; p>=16 -> ((p-16)>>2)*8 + 4 + (p&3).
// This makes the PV B-fragment equal to the QK output registers directly.
// ---------------------------------------------------------------------------
__global__ __launch_bounds__(256) void k_proj(
    const float* __restrict__ xA, const float* __restrict__ xB,
    const float* __restrict__ Wk, const float* __restrict__ bk,
    const float* __restrict__ Wv, const float* __restrict__ bv,
    const float* __restrict__ Wq, const float* __restrict__ bq,
    short* __restrict__ vT, short* __restrict__ qT, short* __restrict__ kC)
{
    int mode = blockIdx.y;
    const float* W    = mode == 0 ? Wk : (mode == 1 ? Wv : Wq);
    const float* bias = mode == 0 ? bk : (mode == 1 ? bv : bq);
    const float* X    = mode == 2 ? xB : xA;

    __shared__ float sW[CI * CC];
    __shared__ float sb[CI];
    __shared__ float spart[3][64][33];
    for (int i = threadIdx.x; i < CI * CC; i += 256) sW[i] = W[i];
    if (threadIdx.x < CI) sb[threadIdx.x] = bias[threadIdx.x];
    __syncthreads();

    int q4 = threadIdx.x >> 6;      // c-quarter
    int lp = threadIdx.x & 63;      // local pixel
    int idx = blockIdx.x * 64 + lp; // 0 .. NBATCH*NPIX-1
    int b = idx / NPIX, n = idx % NPIX;

    float acc[CI];
    #pragma unroll
    for (int o = 0; o < CI; o++) acc[o] = 0.f;

    const float* px = X + (size_t)b * CC * NPIX + n;
    #pragma unroll
    for (int cc = 0; cc < 16; cc++) {
        int c = q4 * 16 + cc;
        float x = px[(size_t)c * NPIX];
        #pragma unroll
        for (int o = 0; o < CI; o++) acc[o] += sW[o * CC + c] * x;
    }
    if (q4) {
        #pragma unroll
        for (int o = 0; o < CI; o++) spart[q4 - 1][lp][o] = acc[o];
    }
    __syncthreads();
    if (q4 == 0) {
        #pragma unroll
        for (int o = 0; o < CI; o++)
            acc[o] += spart[0][lp][o] + spart[1][lp][o] + spart[2][lp][o] + sb[o];
        if (mode == 0) {
            int p = n & 31;
            int pc = (p < 16) ? ((p >> 2) * 8 + (p & 3))
                              : (((p - 16) >> 2) * 8 + 4 + (p & 3));
            int ncol = (n & ~31) + pc;
            #pragma unroll
            for (int o = 0; o < CI; o++)
                kC[((size_t)b * CI + o) * NPIX + ncol] = f2b(acc[o]);
        } else {
            float sc = (mode == 2) ? LOG2E : 1.0f;
            short* dst = (mode == 1 ? vT : qT) + ((size_t)b * NPIX + n) * CI;
            #pragma unroll
            for (int v4 = 0; v4 < 4; v4++) {
                u32x4 pk;
                #pragma unroll
                for (int j = 0; j < 4; j++)
                    pk[j] = cvtpk(acc[v4 * 8 + 2 * j] * sc, acc[v4 * 8 + 2 * j + 1] * sc);
                ((u32x4*)dst)[v4] = pk;
            }
        }
    }
}

// ---------------------------------------------------------------------------
// K1: sum_part[z][b][n] = sum over m-slice of exp2(S'[n,m]).
// 128-thr (2 waves); wave handles 32 n-rows; prefetched q fragments.
// ---------------------------------------------------------------------------
__global__ __launch_bounds__(128) void k_denom(
    const short* __restrict__ vT, const short* __restrict__ qT,
    float* __restrict__ sum_part)
{
    int w = threadIdx.x >> 6, lane = threadIdx.x & 63;
    int r = lane & 15, g = lane >> 4;
    int b = blockIdx.y;
    int nb = blockIdx.x * 64 + w * 32;

    const short* vb = vT + (size_t)b * NPIX * CI;
    s16x8 a0 = *(const s16x8*)(vb + (size_t)(nb + r) * CI + 8 * g);
    s16x8 a1 = *(const s16x8*)(vb + (size_t)(nb + 16 + r) * CI + 8 * g);

    f32x4 s0 = {0.f, 0.f, 0.f, 0.f}, s1 = {0.f, 0.f, 0.f, 0.f};
    f32x4 z  = {0.f, 0.f, 0.f, 0.f};
    const short* qb = qT + (size_t)b * NPIX * CI;
    int mlo = blockIdx.z * (NPIX / NSD);
    int mhi = mlo + NPIX / NSD;

    s16x8 q0 = *(const s16x8*)(qb + (size_t)(mlo + r) * CI + 8 * g);
    s16x8 q1 = *(const s16x8*)(qb + (size_t)(mlo + 16 + r) * CI + 8 * g);
    for (int m0 = mlo; m0 < mhi; m0 += 32) {
        int np = (m0 + 32 < mhi) ? m0 + 32 : mlo;
        s16x8 nq0 = *(const s16x8*)(qb + (size_t)(np + r) * CI + 8 * g);
        s16x8 nq1 = *(const s16x8*)(qb + (size_t)(np + 16 + r) * CI + 8 * g);

        f32x4 t00 = __builtin_amdgcn_mfma_f32_16x16x32_bf16(a0, q0, z, 0, 0, 0);
        f32x4 t01 = __builtin_amdgcn_mfma_f32_16x16x32_bf16(a0, q1, z, 0, 0, 0);
        f32x4 t10 = __builtin_amdgcn_mfma_f32_16x16x32_bf16(a1, q0, z, 0, 0, 0);
        f32x4 t11 = __builtin_amdgcn_mfma_f32_16x16x32_bf16(a1, q1, z, 0, 0, 0);
        #pragma unroll
        for (int e = 0; e < 4; e++) {
            s0[e] += __builtin_amdgcn_exp2f(t00[e]) + __builtin_amdgcn_exp2f(t01[e]);
            s1[e] += __builtin_amdgcn_exp2f(t10[e]) + __builtin_amdgcn_exp2f(t11[e]);
        }
        q0 = nq0; q1 = nq1;
    }
    #pragma unroll
    for (int mask = 1; mask < 16; mask <<= 1) {
        #pragma unroll
        for (int e = 0; e < 4; e++) {
            s0[e] += __shfl_xor(s0[e], mask, 64);
            s1[e] += __shfl_xor(s1[e], mask, 64);
        }
    }
    if (r == 0) {
        float* sp = sum_part + ((size_t)blockIdx.z * NBATCH + b) * NPIX;
        #pragma unroll
        for (int e = 0; e < 4; e++) {
            sp[nb + 4 * g + e]      = s0[e];
            sp[nb + 16 + 4 * g + e] = s1[e];
        }
    }
}

// ---------------------------------------------------------------------------
// K1b: nl2d[b][n] = -log2( sum_z sum_part[z][b][n] )
// ---------------------------------------------------------------------------
__global__ __launch_bounds__(256) void k_l2d(
    const float* __restrict__ sum_part, float* __restrict__ nl2d)
{
    int idx = blockIdx.x * 256 + threadIdx.x;   // b*NPIX + n
    float s = 0.f;
    #pragma unroll
    for (int zz = 0; zz < NSD; zz++)
        s += sum_part[(size_t)zz * NBATCH * NPIX + idx];
    nl2d[idx] = -__builtin_amdgcn_logf(s);
}

// ---------------------------------------------------------------------------
// K2: avp[z][b][m][c] (bf16) = sum over n-slice of k[c,n] * P[n,m],
//     P = exp2(S' - log2 d) via -log2d as QK C-operand.
// NO LDS: kC's K-permuted columns make the PV B-frag equal to the QK output
// registers (t00/t10 quads) after exp+cvtpk. 128-thr, prefetched globals.
// ---------------------------------------------------------------------------
__global__ __launch_bounds__(128) void k_attn(
    const short* __restrict__ vT, const short* __restrict__ qT,
    const short* __restrict__ kC, const float* __restrict__ nl2d,
    short* __restrict__ avp, int slice)
{
    int w = threadIdx.x >> 6, lane = threadIdx.x & 63;
    int r = lane & 15, g = lane >> 4;
    int b = blockIdx.y;
    int m0 = blockIdx.x * 64 + w * 32;

    const short* qb = qT + (size_t)b * NPIX * CI;
    s16x8 qb0 = *(const s16x8*)(qb + (size_t)(m0 + r) * CI + 8 * g);
    s16x8 qb1 = *(const s16x8*)(qb + (size_t)(m0 + 16 + r) * CI + 8 * g);

    const short* vb = vT + (size_t)b * NPIX * CI;
    const short* k0 = kC + ((size_t)b * CI + r) * NPIX;
    const short* k1 = k0 + (size_t)16 * NPIX;
    const float* nl2 = nl2d + (size_t)b * NPIX;

    f32x4 acc00 = {0,0,0,0}, acc01 = {0,0,0,0}, acc10 = {0,0,0,0}, acc11 = {0,0,0,0};

    int nlo = blockIdx.z * slice;
    int nhi = nlo + slice;

    s16x8 a0  = *(const s16x8*)(vb + (size_t)(nlo + r) * CI + 8 * g);
    s16x8 a1  = *(const s16x8*)(vb + (size_t)(nlo + 16 + r) * CI + 8 * g);
    s16x8 ka0 = *(const s16x8*)(k0 + nlo + 8 * g);
    s16x8 ka1 = *(const s16x8*)(k1 + nlo + 8 * g);

    for (int n0 = nlo; n0 < nhi; n0 += 32) {
        int np = (n0 + 32 < nhi) ? n0 + 32 : nlo;
        s16x8 na0  = *(const s16x8*)(vb + (size_t)(np + r) * CI + 8 * g);
        s16x8 na1  = *(const s16x8*)(vb + (size_t)(np + 16 + r) * CI + 8 * g);
        s16x8 nka0 = *(const s16x8*)(k0 + np + 8 * g);
        s16x8 nka1 = *(const s16x8*)(k1 + np + 8 * g);

        f32x4 c0 = *(const f32x4*)(nl2 + n0 + 4 * g);        // rows n0+4g+e
        f32x4 c1 = *(const f32x4*)(nl2 + n0 + 16 + 4 * g);   // rows n0+16+4g+e

        f32x4 t00 = __builtin_amdgcn_mfma_f32_16x16x32_bf16(a0, qb0, c0, 0, 0, 0);
        f32x4 t01 = __builtin_amdgcn_mfma_f32_16x16x32_bf16(a0, qb1, c0, 0, 0, 0);
        f32x4 t10 = __builtin_amdgcn_mfma_f32_16x16x32_bf16(a1, qb0, c1, 0, 0, 0);
        f32x4 t11 = __builtin_amdgcn_mfma_f32_16x16x32_bf16(a1, qb1, c1, 0, 0, 0);

        // P fragments directly in-register (kC columns are K-permuted):
        // pb = [t00 e01, t00 e23, t10 e01, t10 e23]
        u32x4 p0, p1;
        p0[0] = cvtpk(__builtin_amdgcn_exp2f(t00[0]), __builtin_amdgcn_exp2f(t00[1]));
        p0[1] = cvtpk(__builtin_amdgcn_exp2f(t00[2]), __builtin_amdgcn_exp2f(t00[3]));
        p0[2] = cvtpk(__builtin_amdgcn_exp2f(t10[0]), __builtin_amdgcn_exp2f(t10[1]));
        p0[3] = cvtpk(__builtin_amdgcn_exp2f(t10[2]), __builtin_amdgcn_exp2f(t10[3]));
        p1[0] = cvtpk(__builtin_amdgcn_exp2f(t01[0]), __builtin_amdgcn_exp2f(t01[1]));
        p1[1] = cvtpk(__builtin_amdgcn_exp2f(t01[2]), __builtin_amdgcn_exp2f(t01[3]));
        p1[2] = cvtpk(__builtin_amdgcn_exp2f(t11[0]), __builtin_amdgcn_exp2f(t11[1]));
        p1[3] = cvtpk(__builtin_amdgcn_exp2f(t11[2]), __builtin_amdgcn_exp2f(t11[3]));
        s16x8 pb0 = asS16x8(p0);
        s16x8 pb1 = asS16x8(p1);

        acc00 = __builtin_amdgcn_mfma_f32_16x16x32_bf16(ka0, pb0, acc00, 0, 0, 0);
        acc10 = __builtin_amdgcn_mfma_f32_16x16x32_bf16(ka1, pb0, acc10, 0, 0, 0);
        acc01 = __builtin_amdgcn_mfma_f32_16x16x32_bf16(ka0, pb1, acc01, 0, 0, 0);
        acc11 = __builtin_amdgcn_mfma_f32_16x16x32_bf16(ka1, pb1, acc11, 0, 0, 0);

        a0 = na0; a1 = na1; ka0 = nka0; ka1 = nka1;
    }

    short* dst = avp + ((size_t)blockIdx.z * NBATCH + b) * NPIX * CI;
    u32x2 o00 = {cvtpk(acc00[0], acc00[1]), cvtpk(acc00[2], acc00[3])};
    u32x2 o10 = {cvtpk(acc10[0], acc10[1]), cvtpk(acc10[2], acc10[3])};
    u32x2 o01 = {cvtpk(acc01[0], acc01[1]), cvtpk(acc01[2], acc01[3])};
    u32x2 o11 = {cvtpk(acc11[0], acc11[1]), cvtpk(acc11[2], acc11[3])};
    *(u32x2*)(dst + (size_t)(m0 + r) * CI + 4 * g)           = o00;
    *(u32x2*)(dst + (size_t)(m0 + r) * CI + 16 + 4 * g)      = o10;
    *(u32x2*)(dst + (size_t)(m0 + 16 + r) * CI + 4 * g)      = o01;
    *(u32x2*)(dst + (size_t)(m0 + 16 + r) * CI + 16 + 4 * g) = o11;
}

// ---------------------------------------------------------------------------
// E0: av[b][m][c] (bf16) = sum_z avp[z][b][m][c]; one u32 (2 ch) per thread
// ---------------------------------------------------------------------------
__global__ __launch_bounds__(256) void e_red(
    const short* __restrict__ avp, short* __restrict__ av, int nsa)
{
    int idx = blockIdx.x * 256 + threadIdx.x;   // over NBATCH*NPIX*CI/2 u32s
    const unsigned* src = (const unsigned*)avp;
    float lo = 0.f, hi = 0.f;
    for (int zz = 0; zz < nsa; zz++) {
        unsigned p = src[(size_t)zz * (NBATCH * NPIX * CI / 2) + idx];
        lo += b2f((short)(p & 0xFFFF));
        hi += b2f((short)(p >> 16));
    }
    ((unsigned*)av)[idx] = cvtpk(lo, hi);
}

// ---------------------------------------------------------------------------
// E1 (MFMA): out = relu( BN2( Wo @ BN1(Wg @ av) + bo ) + xB )
// 256 thr = 4 waves; each wave handles 16 pixels (MFMA j-dim), 6 MFMAs.
// ---------------------------------------------------------------------------
__global__ __launch_bounds__(256) void e_fused(
    const short* __restrict__ av,
    const float* __restrict__ Wg,
    const float* __restrict__ g1g, const float* __restrict__ g1b,
    const float* __restrict__ g1m, const float* __restrict__ g1v,
    const float* __restrict__ Wo, const float* __restrict__ bo,
    const float* __restrict__ g2g, const float* __restrict__ g2b,
    const float* __restrict__ g2m, const float* __restrict__ g2v,
    const float* __restrict__ xB, float* __restrict__ out)
{
    __shared__ float s1s[CI], t1s[CI], s2s[CC], t2s[CC];
    __shared__ short sa2[4][16][36];
    int t = threadIdx.x;
    if (t < CC) {
        float s = g2g[t] * rsqrtf(g2v[t] + 1e-5f);
        s2s[t] = s; t2s[t] = g2b[t] - g2m[t] * s + bo[t] * s;
    } else if (t < CC + CI) {
        int o = t - CC;
        float s = g1g[o] * rsqrtf(g1v[o] + 1e-5f);
        s1s[o] = s; t1s[o] = g1b[o] - g1m[o] * s;
    }
    __syncthreads();

    int w = t >> 6, lane = t & 63;
    int r = lane & 15, g = lane >> 4;
    int idx0 = blockIdx.x * 64 + w * 16;        // flat pixel base (b*NPIX+m)
    int b = idx0 / NPIX;
    int mcol = (idx0 % NPIX) + r;

    const float* wg0 = Wg + r * CI + 8 * g;
    const float* wg1 = Wg + (16 + r) * CI + 8 * g;
    float sA = s1s[r], sB = s1s[16 + r];
    u32x4 a1l, a1h;
    #pragma unroll
    for (int j = 0; j < 4; j++) {
        a1l[j] = cvtpk(wg0[2 * j] * sA, wg0[2 * j + 1] * sA);
        a1h[j] = cvtpk(wg1[2 * j] * sB, wg1[2 * j + 1] * sB);
    }
    s16x8 A1lo = asS16x8(a1l), A1hi = asS16x8(a1h);

    s16x8 Bav = *(const s16x8*)(av + (size_t)(idx0 + r) * CI + 8 * g);

    f32x4 z = {0, 0, 0, 0};
    f32x4 d1lo = __builtin_amdgcn_mfma_f32_16x16x32_bf16(A1lo, Bav, z, 0, 0, 0);
    f32x4 d1hi = __builtin_amdgcn_mfma_f32_16x16x32_bf16(A1hi, Bav, z, 0, 0, 0);

    u32x2 plo = {cvtpk(d1lo[0] + t1s[4 * g],     d1lo[1] + t1s[4 * g + 1]),
                 cvtpk(d1lo[2] + t1s[4 * g + 2], d1lo[3] + t1s[4 * g + 3])};
    u32x2 phi = {cvtpk(d1hi[0] + t1s[16 + 4 * g],     d1hi[1] + t1s[16 + 4 * g + 1]),
                 cvtpk(d1hi[2] + t1s[16 + 4 * g + 2], d1hi[3] + t1s[16 + 4 * g + 3])};
    *(u32x2*)&sa2[w][r][4 * g]      = plo;
    *(u32x2*)&sa2[w][r][16 + 4 * g] = phi;

    s16x4 l0 = *(const s16x4*)&sa2[w][r][8 * g];
    s16x4 h0 = *(const s16x4*)&sa2[w][r][8 * g + 4];
    s16x8 B2 = {l0[0], l0[1], l0[2], l0[3], h0[0], h0[1], h0[2], h0[3]};

    #pragma unroll
    for (int h = 0; h < 4; h++) {
        const float* wo = Wo + (size_t)(16 * h + r) * CI + 8 * g;
        float s = s2s[16 * h + r];
        u32x4 aw;
        #pragma unroll
        for (int j = 0; j < 4; j++)
            aw[j] = cvtpk(wo[2 * j] * s, wo[2 * j + 1] * s);
        f32x4 d2 = __builtin_amdgcn_mfma_f32_16x16x32_bf16(asS16x8(aw), B2, z, 0, 0, 0);
        #pragma unroll
        for (int e = 0; e < 4; e++) {
            int ch = 16 * h + 4 * g + e;
            size_t oi = ((size_t)b * CC + ch) * NPIX + mcol;
            float v = d2[e] + t2s[ch] + xB[oi];
            out[oi] = v > 0.f ? v : 0.f;
        }
    }
}

// ---------------------------------------------------------------------------
extern "C" void kernel_launch(void* const* d_in, const int* in_sizes, int n_in,
                              void* d_out, int out_size, void* d_ws, size_t ws_size,
                              hipStream_t stream)
{
    const float* xA = (const float*)d_in[0];
    const float* xB = (const float*)d_in[1];
    const float* Wk = (const float*)d_in[2];
    const float* bk = (const float*)d_in[3];
    const float* Wv = (const float*)d_in[4];
    const float* bv = (const float*)d_in[5];
    const float* Wq = (const float*)d_in[6];
    const float* bq = (const float*)d_in[7];
    const float* Wg = (const float*)d_in[8];
    const float* g1g = (const float*)d_in[9];
    const float* g1b = (const float*)d_in[10];
    const float* g1m = (const float*)d_in[11];
    const float* g1v = (const float*)d_in[12];
    const float* Wo = (const float*)d_in[13];
    const float* bo = (const float*)d_in[14];
    const float* g2g = (const float*)d_in[15];
    const float* g2b = (const float*)d_in[16];
    const float* g2m = (const float*)d_in[17];
    const float* g2v = (const float*)d_in[18];
    float* out = (float*)d_out;

    char* ws = (char*)d_ws;
    const size_t SZB = (size_t)NBATCH * NPIX * CI * 2;       // 1,179,648 B
    short* vT = (short*)(ws);                                 // dead after k_attn
    short* qT = (short*)(ws + SZB);
    short* kC = (short*)(ws + 2 * SZB);
    float* nl2d = (float*)(ws + 3 * SZB);                     // NBATCH*NPIX f32
    char*  region = ws + 3 * SZB + (size_t)NBATCH * NPIX * 4;
    float* sum_part = (float*)region;                         // dead after k_l2d
    short* avp = (short*)region;                              // overlays sum_part
    short* av = vT;                                           // overlays vT

    // pick attention n-split by available workspace
    const size_t base = 3 * SZB + (size_t)NBATCH * NPIX * 4;
    int nsa = (ws_size >= base + (size_t)16 * NBATCH * NPIX * CI * 2) ? 16 : 8;
    int slice = NPIX / nsa;   // 576 or 1152

    k_proj<<<dim3(NBATCH * NPIX / 64, 3), dim3(256), 0, stream>>>(
        xA, xB, Wk, bk, Wv, bv, Wq, bq, vT, qT, kC);
    k_denom<<<dim3(NPIX / 64, NBATCH, NSD), dim3(128), 0, stream>>>(
        vT, qT, sum_part);
    k_l2d<<<dim3(NBATCH * NPIX / 256), dim3(256), 0, stream>>>(
        sum_part, nl2d);
    k_attn<<<dim3(NPIX / 64, NBATCH, nsa), dim3(128), 0, stream>>>(
        vT, qT, kC, nl2d, avp, slice);
    e_red<<<dim3(NBATCH * NPIX * CI / 2 / 256), dim3(256), 0, stream>>>(
        avp, av, nsa);
    e_fused<<<dim3(NBATCH * NPIX / 64), dim3(256), 0, stream>>>(
        av, Wg, g1g, g1b, g1m, g1v, Wo, bo, g2g, g2b, g2m, g2v, xB, out);
}